// Round 10
// baseline (230.396 us; speedup 1.0000x reference)
//
#include <hip/hip_runtime.h>
#include <hip/hip_bf16.h>

#define N_NODES 50000
#define N_EDGES 800000
#define DIN 256
#define HD 128   // H*D
#define NH 4
#define CAP 64   // max total in-degree (Poisson(16): P(>64) ~ 1e-20)
#define NSH 8    // shards = XCD count; shard = blockIdx & 7 (round-robin dispatch)
#define SCAP 16  // per-shard cell cap: Poisson(2) tail; cell = exactly one 64B line

#define GROWS 64     // rows per GEMM block (4 waves x 16)
#define LDKH 136     // LDS k-stride for a K=128 half (272 B row: 16B-aligned)

#define GEMM_BLOCKS ((N_NODES + GROWS - 1) / GROWS)   // 782
#define SCAT_BLOCKS ((N_EDGES + 255) / 256)           // 3125

typedef __bf16 bf16x8 __attribute__((ext_vector_type(8)));
typedef float  f32x4  __attribute__((ext_vector_type(4)));

static __device__ __forceinline__ unsigned short f2bu(float v) {
  union { __hip_bfloat16 b; unsigned short u; } c;
  c.b = __float2bfloat16(v);
  return c.u;
}

static __device__ __forceinline__ unsigned short f2hu(float v) {
  union { _Float16 h; unsigned short u; } c;
  c.h = (_Float16)v;
  return c.u;
}

static __device__ __forceinline__ float hu2f(unsigned short u) {
  union { _Float16 h; unsigned short u; } c;
  c.u = u;
  return (float)c.h;
}

// ---------------- init: W -> fragment-linear bf16 WtF (cursor via memset) ----
__global__ void init_kernel(const float* __restrict__ W,
                            unsigned short* __restrict__ WtF) {
  int i = blockIdx.x * 256 + threadIdx.x;
  if (i < HD * DIN) {
    int j    = i & 7;
    int lane = (i >> 3) & 63;
    int t    = (i >> 9) & 7;
    int s    = (i >> 12) & 3;
    int ks   = (i >> 14) & 1;
    int m = lane & 15, q = lane >> 4;
    int k = ks * 128 + 32 * s + 8 * q + j;
    int c = 16 * t + m;
    WtF[i] = f2bu(W[k * HD + c]);
  }
}

// ---------------- scatter: XCD-sharded buckets -------------------------------
// Round-9 isolated scatter = 70us with everything idle: the cost is device-
// scope RMW line-bouncing — each dst's counter/cell is touched by ~16 edges
// from RANDOM XCDs (per-XCD L2s non-coherent -> every RMW migrates the line).
// Cursor padding (r1->r2 null) killed false sharing; TRUE sharing remained.
// Fix: shard by blockIdx&7 (round-robin block->XCD dispatch). cursor_s is
// shard-major (line = 16 dst counters of ONE shard); a slot cell = one 64B
// line written by one XCD; its ~2 entries merge in the local L2.
__global__ __launch_bounds__(256, 4) void scatter_kernel(
    const int2* __restrict__ adj,
    const float* __restrict__ wts,
    int* __restrict__ cursor_s,          // [NSH][N_NODES]
    unsigned int* __restrict__ slots_s) { // [NSH][N_NODES][SCAP]
  int e = blockIdx.x * 256 + threadIdx.x;
  if (e >= N_EDGES) return;
  const int shard = blockIdx.x & (NSH - 1);
  int2 sd = adj[e];                      // x = src, y = dst
  if ((unsigned)sd.x >= (unsigned)N_NODES || (unsigned)sd.y >= (unsigned)N_NODES) return;
  float g = fmaxf(wts[e], 1e-6f);
  int pos = atomicAdd(&cursor_s[shard * N_NODES + sd.y], 1);
  if (pos >= SCAP) pos = SCAP - 1;       // Poisson(2) tail ~1e-10/cell; never corrupt OOB
  unsigned packed = ((unsigned)f2hu(g) << 16) | (unsigned)(sd.x & 0xffff);
  slots_s[((size_t)shard * N_NODES + sd.y) * SCAP + pos] = packed;
}

// ---------------- GEMM kernel (round-5 ILP body, unchanged) ------------------
__global__ __launch_bounds__(256, 2) void gemm_kernel(
    const float* __restrict__ x,
    const unsigned short* __restrict__ WtF,  // fragment-linear bf16 [32768]
    const float* __restrict__ a_src,
    const float* __restrict__ a_dst,
    unsigned short* __restrict__ hbf,        // bf16 bits [N_NODES][HD]
    float* __restrict__ ssrc,
    float* __restrict__ sdst) {
  __shared__ unsigned short xs[GROWS * LDKH];   // 17,408 B
  const int tid = threadIdx.x;

  const int row0 = blockIdx.x * GROWS;
  const int wid  = tid >> 6;      // wave id -> row stripe
  const int lane = tid & 63;
  const int m    = lane & 15;     // A row within tile / B col within tile
  const int q    = lane >> 4;     // quad

  float4 v0[8];
#pragma unroll
  for (int it = 0; it < 8; it++) {
    int i = it * 256 + tid, r = i >> 5, kq = i & 31;
    int row = row0 + r;
    v0[it] = (row < N_NODES) ? *(const float4*)(x + (size_t)row * DIN + 4 * kq)
                             : make_float4(0.f, 0.f, 0.f, 0.f);
  }
#pragma unroll
  for (int it = 0; it < 8; it++) {
    int i = it * 256 + tid, r = i >> 5, kq = i & 31;
    ushort4 b;
    b.x = f2bu(v0[it].x); b.y = f2bu(v0[it].y); b.z = f2bu(v0[it].z); b.w = f2bu(v0[it].w);
    *(ushort4*)&xs[r * LDKH + 4 * kq] = b;
  }
  __syncthreads();

  f32x4 acc[8];
#pragma unroll
  for (int t = 0; t < 8; t++) acc[t] = (f32x4){0.f, 0.f, 0.f, 0.f};

  const unsigned short* xbase = &xs[(wid * 16 + m) * LDKH];

  bf16x8 a0[4];
#pragma unroll
  for (int s = 0; s < 4; s++) a0[s] = *(const bf16x8*)(xbase + 32 * s + 8 * q);

  float4 v1[8];   // prefetch half 1 under half-0 MFMAs
#pragma unroll
  for (int it = 0; it < 8; it++) {
    int i = it * 256 + tid, r = i >> 5, kq = i & 31;
    int row = row0 + r;
    v1[it] = (row < N_NODES) ? *(const float4*)(x + (size_t)row * DIN + 128 + 4 * kq)
                             : make_float4(0.f, 0.f, 0.f, 0.f);
  }

#pragma unroll
  for (int s = 0; s < 4; s++) {
    bf16x8 bfr[8];
#pragma unroll
    for (int t = 0; t < 8; t++)
      bfr[t] = *(const bf16x8*)(WtF + (size_t)((0 * 4 + s) * 8 + t) * 512 + lane * 8);
#pragma unroll
    for (int t = 0; t < 8; t++)
      acc[t] = __builtin_amdgcn_mfma_f32_16x16x32_bf16(a0[s], bfr[t], acc[t], 0, 0, 0);
  }
  __syncthreads();   // all half-0 xs reads complete before overwrite

#pragma unroll
  for (int it = 0; it < 8; it++) {
    int i = it * 256 + tid, r = i >> 5, kq = i & 31;
    ushort4 b;
    b.x = f2bu(v1[it].x); b.y = f2bu(v1[it].y); b.z = f2bu(v1[it].z); b.w = f2bu(v1[it].w);
    *(ushort4*)&xs[r * LDKH + 4 * kq] = b;
  }
  __syncthreads();

  bf16x8 a1[4];
#pragma unroll
  for (int s = 0; s < 4; s++) a1[s] = *(const bf16x8*)(xbase + 32 * s + 8 * q);

#pragma unroll
  for (int s = 0; s < 4; s++) {
    bf16x8 bfr[8];
#pragma unroll
    for (int t = 0; t < 8; t++)
      bfr[t] = *(const bf16x8*)(WtF + (size_t)((1 * 4 + s) * 8 + t) * 512 + lane * 8);
#pragma unroll
    for (int t = 0; t < 8; t++)
      acc[t] = __builtin_amdgcn_mfma_f32_16x16x32_bf16(a1[s], bfr[t], acc[t], 0, 0, 0);
  }

  // D layout: lane holds rows q*4+r (r=0..3), col m of each tile t.
#pragma unroll
  for (int t = 0; t < 8; t++) {
#pragma unroll
    for (int r = 0; r < 4; r++) {
      int row = row0 + wid * 16 + q * 4 + r;
      if (row < N_NODES) hbf[(size_t)row * HD + 16 * t + m] = f2bu(acc[t][r]);
    }
  }

  float as[8], ad[8];
#pragma unroll
  for (int t = 0; t < 8; t++) {
    as[t] = a_src[16 * t + m];
    ad[t] = a_dst[16 * t + m];
  }
#pragma unroll
  for (int r = 0; r < 4; r++) {
    float ps[NH] = {0.f, 0.f, 0.f, 0.f};
    float pd[NH] = {0.f, 0.f, 0.f, 0.f};
#pragma unroll
    for (int t = 0; t < 8; t++) {
      ps[t >> 1] = fmaf(acc[t][r], as[t], ps[t >> 1]);
      pd[t >> 1] = fmaf(acc[t][r], ad[t], pd[t >> 1]);
    }
#pragma unroll
    for (int mm = 8; mm >= 1; mm >>= 1) {   // reduce across the 16 lanes of quad q
#pragma unroll
      for (int hh = 0; hh < NH; hh++) {
        ps[hh] += __shfl_xor(ps[hh], mm, 64);
        pd[hh] += __shfl_xor(pd[hh], mm, 64);
      }
    }
    int row = row0 + wid * 16 + q * 4 + r;
    if (m == 0 && row < N_NODES) {
#pragma unroll
      for (int hh = 0; hh < NH; hh++) {
        ssrc[row * NH + hh] = ps[hh];
        sdst[row * NH + hh] = pd[hh];
      }
    }
  }
}

// ---------------- per-node: gather 8 shard segments + round-5 body -----------
__global__ __launch_bounds__(128, 4) void node_kernel(
    const int* __restrict__ cursor_s,         // [NSH][N_NODES]
    const unsigned int* __restrict__ slots_s, // [NSH][N_NODES][SCAP]
    const float4* __restrict__ ssrc4,
    const float4* __restrict__ sdst4,
    const unsigned int* __restrict__ hbf32,   // bf16 pairs
    float* __restrict__ out) {
  const int tid  = threadIdx.x;
  const int wid  = tid >> 6;           // 0/1: which node
  const int lane = tid & 63;
  const int n    = blockIdx.x * 2 + wid;
  const int hh   = lane >> 4;          // head of cols 2l,2l+1

  __shared__ unsigned spk[2][CAP];     // gathered packed entries
  __shared__ int    sidx[2][CAP];
  __shared__ float4 swv[2][CAP];

  // ---- gather shard segments (8 independent guarded cell reads) ----
  int c[NSH], o[NSH];
  int tot = 0;
#pragma unroll
  for (int s = 0; s < NSH; s++) {
    int cs = cursor_s[s * N_NODES + n];   // wave-uniform address -> broadcast
    cs = (cs < SCAP) ? cs : SCAP;
    c[s] = cs;
    o[s] = tot;
    tot += cs;
  }
  const int deg = (tot < CAP) ? tot : CAP;
#pragma unroll
  for (int s = 0; s < NSH; s++) {
    if (lane < c[s]) {
      int d = o[s] + lane;
      if (d < CAP)
        spk[wid][d] = slots_s[((size_t)s * N_NODES + n) * SCAP + lane];
    }
  }
  __syncthreads();   // spk visible

  float4 ex = make_float4(0.f, 0.f, 0.f, 0.f);
  if (lane < deg) {
    unsigned sl = spk[wid][lane];
    int s = (int)(sl & 0xffffu);
    float g = hu2f((unsigned short)(sl >> 16));
    float4 ss = ssrc4[s];        // 0.8 MB buffer: L2-resident gather
    float4 sd = sdst4[n];
    ex.x = g * expf(tanhf(ss.x + sd.x));
    ex.y = g * expf(tanhf(ss.y + sd.y));
    ex.z = g * expf(tanhf(ss.z + sd.z));
    ex.w = g * expf(tanhf(ss.w + sd.w));
    sidx[wid][lane] = s;
    swv[wid][lane] = make_float4(ex.x * g, ex.y * g, ex.z * g, ex.w * g);
  }

  // wave-wide denominator: lanes >= deg contribute 0
  float4 tot4 = ex;
#pragma unroll
  for (int mm = 32; mm >= 1; mm >>= 1) {
    tot4.x += __shfl_xor(tot4.x, mm, 64);
    tot4.y += __shfl_xor(tot4.y, mm, 64);
    tot4.z += __shfl_xor(tot4.z, mm, 64);
    tot4.w += __shfl_xor(tot4.w, mm, 64);
  }
  float dn  = (hh == 0) ? tot4.x : (hh == 1) ? tot4.y : (hh == 2) ? tot4.z : tot4.w;
  float inv = (dn > 0.f) ? 1.f / dn : 0.f;
  __syncthreads();   // sidx/swv visible

  float acc0 = 0.f, acc1 = 0.f;
  int j = 0;
  for (; j + 8 <= deg; j += 8) {
    int s0 = sidx[wid][j + 0], s1 = sidx[wid][j + 1];
    int s2 = sidx[wid][j + 2], s3 = sidx[wid][j + 3];
    int s4 = sidx[wid][j + 4], s5 = sidx[wid][j + 5];
    int s6 = sidx[wid][j + 6], s7 = sidx[wid][j + 7];
    unsigned u0 = hbf32[(size_t)s0 * (HD / 2) + lane];
    unsigned u1 = hbf32[(size_t)s1 * (HD / 2) + lane];
    unsigned u2 = hbf32[(size_t)s2 * (HD / 2) + lane];
    unsigned u3 = hbf32[(size_t)s3 * (HD / 2) + lane];
    unsigned u4 = hbf32[(size_t)s4 * (HD / 2) + lane];
    unsigned u5 = hbf32[(size_t)s5 * (HD / 2) + lane];
    unsigned u6 = hbf32[(size_t)s6 * (HD / 2) + lane];
    unsigned u7 = hbf32[(size_t)s7 * (HD / 2) + lane];
    float w0 = ((const float*)&swv[wid][j + 0])[hh];
    float w1 = ((const float*)&swv[wid][j + 1])[hh];
    float w2 = ((const float*)&swv[wid][j + 2])[hh];
    float w3 = ((const float*)&swv[wid][j + 3])[hh];
    float w4 = ((const float*)&swv[wid][j + 4])[hh];
    float w5 = ((const float*)&swv[wid][j + 5])[hh];
    float w6 = ((const float*)&swv[wid][j + 6])[hh];
    float w7 = ((const float*)&swv[wid][j + 7])[hh];
    acc0 = fmaf(w0, __uint_as_float(u0 << 16), acc0);
    acc1 = fmaf(w0, __uint_as_float(u0 & 0xffff0000u), acc1);
    acc0 = fmaf(w1, __uint_as_float(u1 << 16), acc0);
    acc1 = fmaf(w1, __uint_as_float(u1 & 0xffff0000u), acc1);
    acc0 = fmaf(w2, __uint_as_float(u2 << 16), acc0);
    acc1 = fmaf(w2, __uint_as_float(u2 & 0xffff0000u), acc1);
    acc0 = fmaf(w3, __uint_as_float(u3 << 16), acc0);
    acc1 = fmaf(w3, __uint_as_float(u3 & 0xffff0000u), acc1);
    acc0 = fmaf(w4, __uint_as_float(u4 << 16), acc0);
    acc1 = fmaf(w4, __uint_as_float(u4 & 0xffff0000u), acc1);
    acc0 = fmaf(w5, __uint_as_float(u5 << 16), acc0);
    acc1 = fmaf(w5, __uint_as_float(u5 & 0xffff0000u), acc1);
    acc0 = fmaf(w6, __uint_as_float(u6 << 16), acc0);
    acc1 = fmaf(w6, __uint_as_float(u6 & 0xffff0000u), acc1);
    acc0 = fmaf(w7, __uint_as_float(u7 << 16), acc0);
    acc1 = fmaf(w7, __uint_as_float(u7 & 0xffff0000u), acc1);
  }
  for (; j < deg; j++) {
    int s0 = sidx[wid][j];
    unsigned u0 = hbf32[(size_t)s0 * (HD / 2) + lane];
    float w0 = ((const float*)&swv[wid][j])[hh];
    acc0 = fmaf(w0, __uint_as_float(u0 << 16), acc0);
    acc1 = fmaf(w0, __uint_as_float(u0 & 0xffff0000u), acc1);
  }
  acc0 *= inv;
  acc1 *= inv;

  // exact GELU: x * 0.5 * (1 + erf(x/sqrt(2)))
  float2 gl;
  gl.x = 0.5f * acc0 * (1.f + erff(acc0 * 0.70710678118654752f));
  gl.y = 0.5f * acc1 * (1.f + erff(acc1 * 0.70710678118654752f));
  *(float2*)&out[(size_t)n * HD + 2 * lane] = gl;
}

extern "C" void kernel_launch(void* const* d_in, const int* in_sizes, int n_in,
                              void* d_out, int out_size, void* d_ws, size_t ws_size,
                              hipStream_t stream) {
  const float* x     = (const float*)d_in[0];
  const int2*  adj   = (const int2*)d_in[1];
  const float* wts   = (const float*)d_in[2];
  const float* W     = (const float*)d_in[3];
  const float* a_src = (const float*)d_in[4];
  const float* a_dst = (const float*)d_in[5];
  float* out = (float*)d_out;

  char* p = (char*)d_ws;
  auto carve = [&](size_t bytes) {
    char* q = p;
    p += (bytes + 255) & ~(size_t)255;
    return (void*)q;
  };
  // total ~ 42.5 MB
  unsigned short* hbf = (unsigned short*)carve((size_t)N_NODES * HD * sizeof(unsigned short)); // 12.8 MB
  unsigned short* WtF = (unsigned short*)carve((size_t)HD * DIN * sizeof(unsigned short));     // 64 KB
  float* ssrc   = (float*)carve((size_t)N_NODES * NH * sizeof(float));        // 0.8 MB
  float* sdst   = (float*)carve((size_t)N_NODES * NH * sizeof(float));        // 0.8 MB
  unsigned int* slots_s = (unsigned int*)carve((size_t)NSH * N_NODES * SCAP * sizeof(unsigned int)); // 25.6 MB
  int* cursor_s = (int*)carve((size_t)NSH * N_NODES * sizeof(int));           // 1.6 MB

  hipMemsetAsync(cursor_s, 0, (size_t)NSH * N_NODES * sizeof(int), stream);
  init_kernel<<<(HD * DIN + 255) / 256, 256, 0, stream>>>(W, WtF);
  scatter_kernel<<<SCAT_BLOCKS, 256, 0, stream>>>(adj, wts, cursor_s, slots_s);
  gemm_kernel<<<GEMM_BLOCKS, 256, 0, stream>>>(x, WtF, a_src, a_dst, hbf, ssrc, sdst);
  node_kernel<<<N_NODES / 2, 128, 0, stream>>>(cursor_s, slots_s, (const float4*)ssrc,
                                               (const float4*)sdst,
                                               (const unsigned int*)hbf, out);
}

// Round 11
// 195.918 us; speedup vs baseline: 1.1760x; 1.1760x over previous
//
#include <hip/hip_runtime.h>
#include <hip/hip_bf16.h>

#define N_NODES 50000
#define N_EDGES 800000
#define DIN 256
#define HD 128   // H*D
#define NH 4
#define CAP 64   // max total in-degree (Poisson(16): P(>64) ~ 1e-20)
#define NSH 8    // shards = XCD count; shard = blockIdx & 7 (round-robin dispatch)
#define SCAP 16  // per-shard cell cap: Poisson(2) tail; cell = exactly one 64B line

#define GROWS 64     // rows per GEMM block (4 waves x 16)
#define LDKH 136     // LDS k-stride for a K=128 half (272 B row: 16B-aligned)

#define GEMM_BLOCKS ((N_NODES + GROWS - 1) / GROWS)   // 782
#define SCAT_BLOCKS ((N_EDGES + 255) / 256)           // 3125
#define INIT_ITEMS  (NSH * N_NODES)                   // 400000 > HD*DIN

typedef __bf16 bf16x8 __attribute__((ext_vector_type(8)));
typedef float  f32x4  __attribute__((ext_vector_type(4)));

static __device__ __forceinline__ unsigned short f2bu(float v) {
  union { __hip_bfloat16 b; unsigned short u; } c;
  c.b = __float2bfloat16(v);
  return c.u;
}

static __device__ __forceinline__ unsigned short f2hu(float v) {
  union { _Float16 h; unsigned short u; } c;
  c.h = (_Float16)v;
  return c.u;
}

static __device__ __forceinline__ float hu2f(unsigned short u) {
  union { _Float16 h; unsigned short u; } c;
  c.u = u;
  return (float)c.h;
}

// ---------------- init: W -> fragment-linear bf16 WtF AND cursor_s zero ------
__global__ void init_kernel(const float* __restrict__ W,
                            unsigned short* __restrict__ WtF,
                            int* __restrict__ cursor_s) {
  int i = blockIdx.x * 256 + threadIdx.x;
  if (i < HD * DIN) {
    int j    = i & 7;
    int lane = (i >> 3) & 63;
    int t    = (i >> 9) & 7;
    int s    = (i >> 12) & 3;
    int ks   = (i >> 14) & 1;
    int m = lane & 15, q = lane >> 4;
    int k = ks * 128 + 32 * s + 8 * q + j;
    int c = 16 * t + m;
    WtF[i] = f2bu(W[k * HD + c]);
  }
  if (i < INIT_ITEMS) cursor_s[i] = 0;
}

// ---------------- fused: GEMM blocks + XCD-sharded scatter blocks ------------
// Scatter sharded by global blockIdx&7 (round-robin block->XCD): each
// (shard,dst) counter/cell line is RMW'd by ONE XCD only — r9->r10 showed this
// moved scatter off the top (70us -> <61). GEMM: round-5 ILP body.
__global__ __launch_bounds__(256, 2) void fused_gemm_scatter(
    const float* __restrict__ x,
    const unsigned short* __restrict__ WtF,  // fragment-linear bf16 [32768]
    const float* __restrict__ a_src,
    const float* __restrict__ a_dst,
    unsigned short* __restrict__ hbf,        // bf16 bits [N_NODES][HD]
    float* __restrict__ ssrc,
    float* __restrict__ sdst,
    const int2* __restrict__ adj,
    const float* __restrict__ wts,
    int* __restrict__ cursor_s,              // [NSH][N_NODES]
    unsigned int* __restrict__ slots_s) {    // [NSH][N_NODES][SCAP]
  __shared__ unsigned short xs[GROWS * LDKH];   // 17,408 B
  const int tid = threadIdx.x;

  if (blockIdx.x >= GEMM_BLOCKS) {
    // ---------------- scatter path (sharded) --------------------------------
    int e = (blockIdx.x - GEMM_BLOCKS) * 256 + tid;
    if (e >= N_EDGES) return;
    const int shard = blockIdx.x & (NSH - 1);
    int2 sd = adj[e];                      // x = src, y = dst
    if ((unsigned)sd.x >= (unsigned)N_NODES || (unsigned)sd.y >= (unsigned)N_NODES) return;
    float g = fmaxf(wts[e], 1e-6f);
    int pos = atomicAdd(&cursor_s[shard * N_NODES + sd.y], 1);
    if (pos >= SCAP) pos = SCAP - 1;       // Poisson(2) tail ~1e-10/cell; never corrupt
    unsigned packed = ((unsigned)f2hu(g) << 16) | (unsigned)(sd.x & 0xffff);
    slots_s[((size_t)shard * N_NODES + sd.y) * SCAP + pos] = packed;
    return;
  }

  // ---------------- GEMM path (round-5 ILP body) ----------------------------
  const int row0 = blockIdx.x * GROWS;
  const int wid  = tid >> 6;      // wave id -> row stripe
  const int lane = tid & 63;
  const int m    = lane & 15;     // A row within tile / B col within tile
  const int q    = lane >> 4;     // quad

  float4 v0[8];
#pragma unroll
  for (int it = 0; it < 8; it++) {
    int i = it * 256 + tid, r = i >> 5, kq = i & 31;
    int row = row0 + r;
    v0[it] = (row < N_NODES) ? *(const float4*)(x + (size_t)row * DIN + 4 * kq)
                             : make_float4(0.f, 0.f, 0.f, 0.f);
  }
#pragma unroll
  for (int it = 0; it < 8; it++) {
    int i = it * 256 + tid, r = i >> 5, kq = i & 31;
    ushort4 b;
    b.x = f2bu(v0[it].x); b.y = f2bu(v0[it].y); b.z = f2bu(v0[it].z); b.w = f2bu(v0[it].w);
    *(ushort4*)&xs[r * LDKH + 4 * kq] = b;
  }
  __syncthreads();

  f32x4 acc[8];
#pragma unroll
  for (int t = 0; t < 8; t++) acc[t] = (f32x4){0.f, 0.f, 0.f, 0.f};

  const unsigned short* xbase = &xs[(wid * 16 + m) * LDKH];

  bf16x8 a0[4];
#pragma unroll
  for (int s = 0; s < 4; s++) a0[s] = *(const bf16x8*)(xbase + 32 * s + 8 * q);

  float4 v1[8];   // prefetch half 1 under half-0 MFMAs
#pragma unroll
  for (int it = 0; it < 8; it++) {
    int i = it * 256 + tid, r = i >> 5, kq = i & 31;
    int row = row0 + r;
    v1[it] = (row < N_NODES) ? *(const float4*)(x + (size_t)row * DIN + 128 + 4 * kq)
                             : make_float4(0.f, 0.f, 0.f, 0.f);
  }

#pragma unroll
  for (int s = 0; s < 4; s++) {
    bf16x8 bfr[8];
#pragma unroll
    for (int t = 0; t < 8; t++)
      bfr[t] = *(const bf16x8*)(WtF + (size_t)((0 * 4 + s) * 8 + t) * 512 + lane * 8);
#pragma unroll
    for (int t = 0; t < 8; t++)
      acc[t] = __builtin_amdgcn_mfma_f32_16x16x32_bf16(a0[s], bfr[t], acc[t], 0, 0, 0);
  }
  __syncthreads();   // all half-0 xs reads complete before overwrite

#pragma unroll
  for (int it = 0; it < 8; it++) {
    int i = it * 256 + tid, r = i >> 5, kq = i & 31;
    ushort4 b;
    b.x = f2bu(v1[it].x); b.y = f2bu(v1[it].y); b.z = f2bu(v1[it].z); b.w = f2bu(v1[it].w);
    *(ushort4*)&xs[r * LDKH + 4 * kq] = b;
  }
  __syncthreads();

  bf16x8 a1[4];
#pragma unroll
  for (int s = 0; s < 4; s++) a1[s] = *(const bf16x8*)(xbase + 32 * s + 8 * q);

#pragma unroll
  for (int s = 0; s < 4; s++) {
    bf16x8 bfr[8];
#pragma unroll
    for (int t = 0; t < 8; t++)
      bfr[t] = *(const bf16x8*)(WtF + (size_t)((1 * 4 + s) * 8 + t) * 512 + lane * 8);
#pragma unroll
    for (int t = 0; t < 8; t++)
      acc[t] = __builtin_amdgcn_mfma_f32_16x16x32_bf16(a1[s], bfr[t], acc[t], 0, 0, 0);
  }

  // D layout: lane holds rows q*4+r (r=0..3), col m of each tile t.
#pragma unroll
  for (int t = 0; t < 8; t++) {
#pragma unroll
    for (int r = 0; r < 4; r++) {
      int row = row0 + wid * 16 + q * 4 + r;
      if (row < N_NODES) hbf[(size_t)row * HD + 16 * t + m] = f2bu(acc[t][r]);
    }
  }

  float as[8], ad[8];
#pragma unroll
  for (int t = 0; t < 8; t++) {
    as[t] = a_src[16 * t + m];
    ad[t] = a_dst[16 * t + m];
  }
#pragma unroll
  for (int r = 0; r < 4; r++) {
    float ps[NH] = {0.f, 0.f, 0.f, 0.f};
    float pd[NH] = {0.f, 0.f, 0.f, 0.f};
#pragma unroll
    for (int t = 0; t < 8; t++) {
      ps[t >> 1] = fmaf(acc[t][r], as[t], ps[t >> 1]);
      pd[t >> 1] = fmaf(acc[t][r], ad[t], pd[t >> 1]);
    }
#pragma unroll
    for (int mm = 8; mm >= 1; mm >>= 1) {   // reduce across the 16 lanes of quad q
#pragma unroll
      for (int hh = 0; hh < NH; hh++) {
        ps[hh] += __shfl_xor(ps[hh], mm, 64);
        pd[hh] += __shfl_xor(pd[hh], mm, 64);
      }
    }
    int row = row0 + wid * 16 + q * 4 + r;
    if (m == 0 && row < N_NODES) {
#pragma unroll
      for (int hh = 0; hh < NH; hh++) {
        ssrc[row * NH + hh] = ps[hh];
        sdst[row * NH + hh] = pd[hh];
      }
    }
  }
}

// ---------------- per-node: WAVE-PARALLEL scores + aggregate + GELU ----------
// r10 post-mortem: node = 61us at VALUBusy 68% — the serial-lane softmax
// (16/64 lanes active, 8 libm transcendental sequences/wave) was the cost.
// Now: lane l handles (edge l>>2, head l&3) -> 64 scores/chunk, 1 exp-based
// tanh + 1 __expf per lane per chunk (deg<=16 -> 1 chunk typical); denominator
// is a 4-step butterfly + one shfl redistribution.
__global__ __launch_bounds__(128, 4) void node_kernel(
    const int* __restrict__ cursor_s,         // [NSH][N_NODES]
    const unsigned int* __restrict__ slots_s, // [NSH][N_NODES][SCAP]
    const float* __restrict__ ssrc,           // [N_NODES][NH]
    const float* __restrict__ sdst,           // [N_NODES][NH]
    const unsigned int* __restrict__ hbf32,   // bf16 pairs
    float* __restrict__ out) {
  const int tid  = threadIdx.x;
  const int wid  = tid >> 6;           // 0/1: which node
  const int lane = tid & 63;
  const int n    = blockIdx.x * 2 + wid;
  const int hh   = lane >> 4;          // head for aggregation (cols 2l,2l+1)
  const int hq   = lane & 3;           // head for score phase

  __shared__ unsigned spk[2][CAP];          // gathered packed entries
  __shared__ float    swf[2][CAP * NH];     // alpha-numerator*gate per (edge,head)

  // ---- gather shard segments (8 independent guarded cell reads) ----
  int c[NSH], o[NSH];
  int tot = 0;
#pragma unroll
  for (int s = 0; s < NSH; s++) {
    int cs = cursor_s[s * N_NODES + n];   // wave-uniform address -> broadcast
    cs = (cs < SCAP) ? cs : SCAP;
    c[s] = cs;
    o[s] = tot;
    tot += cs;
  }
  const int deg = (tot < CAP) ? tot : CAP;
#pragma unroll
  for (int s = 0; s < NSH; s++) {
    if (lane < c[s]) {
      int d = o[s] + lane;
      if (d < CAP)
        spk[wid][d] = slots_s[((size_t)s * N_NODES + n) * SCAP + lane];
    }
  }
  __syncthreads();   // spk visible

  // ---- scores: all 64 lanes, chunk of 16 edges x 4 heads ----
  const float sdn = sdst[n * NH + hq];
  float den = 0.f;
  for (int base = 0; base < deg; base += 16) {
    int e = base + (lane >> 2);
    float exv = 0.f;
    if (e < deg) {
      unsigned sl = spk[wid][e];
      int s = (int)(sl & 0xffffu);
      float g = hu2f((unsigned short)(sl >> 16));
      float xx = ssrc[s * NH + hq] + sdn;
      // tanh via exp: 1 - 2/(1+e^{2x}); exact at +-inf, ~1e-7 abs err
      float t = 1.f - 2.f / (1.f + __expf(2.f * xx));
      exv = g * __expf(t);
      swf[wid][e * NH + hq] = exv * g;
    }
    den += exv;
  }
  // reduce across the 16 lanes sharing head hq (xor over bits 2..5)
  den += __shfl_xor(den, 4, 64);
  den += __shfl_xor(den, 8, 64);
  den += __shfl_xor(den, 16, 64);
  den += __shfl_xor(den, 32, 64);
  // lane needs head hh = lane>>4; source lane index hh has hq == hh
  float dh  = __shfl(den, hh, 64);
  float inv = (dh > 0.f) ? 1.f / dh : 0.f;
  __syncthreads();   // swf visible

  // ---- aggregation: unroll-8 gather windows ----
  float acc0 = 0.f, acc1 = 0.f;
  int j = 0;
  for (; j + 8 <= deg; j += 8) {
    int s0 = (int)(spk[wid][j + 0] & 0xffffu), s1 = (int)(spk[wid][j + 1] & 0xffffu);
    int s2 = (int)(spk[wid][j + 2] & 0xffffu), s3 = (int)(spk[wid][j + 3] & 0xffffu);
    int s4 = (int)(spk[wid][j + 4] & 0xffffu), s5 = (int)(spk[wid][j + 5] & 0xffffu);
    int s6 = (int)(spk[wid][j + 6] & 0xffffu), s7 = (int)(spk[wid][j + 7] & 0xffffu);
    unsigned u0 = hbf32[(size_t)s0 * (HD / 2) + lane];
    unsigned u1 = hbf32[(size_t)s1 * (HD / 2) + lane];
    unsigned u2 = hbf32[(size_t)s2 * (HD / 2) + lane];
    unsigned u3 = hbf32[(size_t)s3 * (HD / 2) + lane];
    unsigned u4 = hbf32[(size_t)s4 * (HD / 2) + lane];
    unsigned u5 = hbf32[(size_t)s5 * (HD / 2) + lane];
    unsigned u6 = hbf32[(size_t)s6 * (HD / 2) + lane];
    unsigned u7 = hbf32[(size_t)s7 * (HD / 2) + lane];
    float w0 = swf[wid][(j + 0) * NH + hh];
    float w1 = swf[wid][(j + 1) * NH + hh];
    float w2 = swf[wid][(j + 2) * NH + hh];
    float w3 = swf[wid][(j + 3) * NH + hh];
    float w4 = swf[wid][(j + 4) * NH + hh];
    float w5 = swf[wid][(j + 5) * NH + hh];
    float w6 = swf[wid][(j + 6) * NH + hh];
    float w7 = swf[wid][(j + 7) * NH + hh];
    acc0 = fmaf(w0, __uint_as_float(u0 << 16), acc0);
    acc1 = fmaf(w0, __uint_as_float(u0 & 0xffff0000u), acc1);
    acc0 = fmaf(w1, __uint_as_float(u1 << 16), acc0);
    acc1 = fmaf(w1, __uint_as_float(u1 & 0xffff0000u), acc1);
    acc0 = fmaf(w2, __uint_as_float(u2 << 16), acc0);
    acc1 = fmaf(w2, __uint_as_float(u2 & 0xffff0000u), acc1);
    acc0 = fmaf(w3, __uint_as_float(u3 << 16), acc0);
    acc1 = fmaf(w3, __uint_as_float(u3 & 0xffff0000u), acc1);
    acc0 = fmaf(w4, __uint_as_float(u4 << 16), acc0);
    acc1 = fmaf(w4, __uint_as_float(u4 & 0xffff0000u), acc1);
    acc0 = fmaf(w5, __uint_as_float(u5 << 16), acc0);
    acc1 = fmaf(w5, __uint_as_float(u5 & 0xffff0000u), acc1);
    acc0 = fmaf(w6, __uint_as_float(u6 << 16), acc0);
    acc1 = fmaf(w6, __uint_as_float(u6 & 0xffff0000u), acc1);
    acc0 = fmaf(w7, __uint_as_float(u7 << 16), acc0);
    acc1 = fmaf(w7, __uint_as_float(u7 & 0xffff0000u), acc1);
  }
  for (; j < deg; j++) {
    int s0 = (int)(spk[wid][j] & 0xffffu);
    unsigned u0 = hbf32[(size_t)s0 * (HD / 2) + lane];
    float w0 = swf[wid][j * NH + hh];
    acc0 = fmaf(w0, __uint_as_float(u0 << 16), acc0);
    acc1 = fmaf(w0, __uint_as_float(u0 & 0xffff0000u), acc1);
  }
  acc0 *= inv;
  acc1 *= inv;

  // exact GELU: x * 0.5 * (1 + erf(x/sqrt(2)))
  float2 gl;
  gl.x = 0.5f * acc0 * (1.f + erff(acc0 * 0.70710678118654752f));
  gl.y = 0.5f * acc1 * (1.f + erff(acc1 * 0.70710678118654752f));
  *(float2*)&out[(size_t)n * HD + 2 * lane] = gl;
}

extern "C" void kernel_launch(void* const* d_in, const int* in_sizes, int n_in,
                              void* d_out, int out_size, void* d_ws, size_t ws_size,
                              hipStream_t stream) {
  const float* x     = (const float*)d_in[0];
  const int2*  adj   = (const int2*)d_in[1];
  const float* wts   = (const float*)d_in[2];
  const float* W     = (const float*)d_in[3];
  const float* a_src = (const float*)d_in[4];
  const float* a_dst = (const float*)d_in[5];
  float* out = (float*)d_out;

  char* p = (char*)d_ws;
  auto carve = [&](size_t bytes) {
    char* q = p;
    p += (bytes + 255) & ~(size_t)255;
    return (void*)q;
  };
  // total ~ 42.5 MB
  unsigned short* hbf = (unsigned short*)carve((size_t)N_NODES * HD * sizeof(unsigned short)); // 12.8 MB
  unsigned short* WtF = (unsigned short*)carve((size_t)HD * DIN * sizeof(unsigned short));     // 64 KB
  float* ssrc   = (float*)carve((size_t)N_NODES * NH * sizeof(float));        // 0.8 MB
  float* sdst   = (float*)carve((size_t)N_NODES * NH * sizeof(float));        // 0.8 MB
  unsigned int* slots_s = (unsigned int*)carve((size_t)NSH * N_NODES * SCAP * sizeof(unsigned int)); // 25.6 MB
  int* cursor_s = (int*)carve((size_t)NSH * N_NODES * sizeof(int));           // 1.6 MB

  init_kernel<<<(INIT_ITEMS + 255) / 256, 256, 0, stream>>>(W, WtF, cursor_s);
  fused_gemm_scatter<<<GEMM_BLOCKS + SCAT_BLOCKS, 256, 0, stream>>>(
      x, WtF, a_src, a_dst, hbf, ssrc, sdst, adj, wts, cursor_s, slots_s);
  node_kernel<<<N_NODES / 2, 128, 0, stream>>>(cursor_s, slots_s, ssrc, sdst,
                                               (const unsigned int*)hbf, out);
}

// Round 12
// 195.200 us; speedup vs baseline: 1.1803x; 1.0037x over previous
//
#include <hip/hip_runtime.h>
#include <hip/hip_bf16.h>

#define N_NODES 50000
#define N_EDGES 800000
#define DIN 256
#define HD 128   // H*D
#define NH 4
#define CAP 64   // max total in-degree (Poisson(16): P(>64) ~ 1e-20)
#define NSH 8    // shards = physical XCDs (HW_REG_XCC_ID, m09-verified 0..7)
#define SCAP 16  // per-shard cell cap: Poisson(2) tail; cell = exactly one 64B line

#define GROWS 64     // rows per GEMM block (4 waves x 16)
#define LDKH 136     // LDS k-stride for a K=128 half (272 B row: 16B-aligned)

#define GEMM_BLOCKS ((N_NODES + GROWS - 1) / GROWS)   // 782
#define SCAT_BLOCKS ((N_EDGES + 255) / 256)           // 3125
#define INIT_ITEMS  (NSH * N_NODES)                   // 400000 > HD*DIN

typedef __bf16 bf16x8 __attribute__((ext_vector_type(8)));
typedef float  f32x4  __attribute__((ext_vector_type(4)));

static __device__ __forceinline__ unsigned short f2bu(float v) {
  union { __hip_bfloat16 b; unsigned short u; } c;
  c.b = __float2bfloat16(v);
  return c.u;
}

static __device__ __forceinline__ unsigned short f2hu(float v) {
  union { _Float16 h; unsigned short u; } c;
  c.h = (_Float16)v;
  return c.u;
}

static __device__ __forceinline__ float hu2f(unsigned short u) {
  union { _Float16 h; unsigned short u; } c;
  c.u = u;
  return (float)c.h;
}

// ---------------- init: W -> fragment-linear bf16 WtF AND cursor_s zero ------
__global__ void init_kernel(const float* __restrict__ W,
                            unsigned short* __restrict__ WtF,
                            int* __restrict__ cursor_s) {
  int i = blockIdx.x * 256 + threadIdx.x;
  if (i < HD * DIN) {
    int j    = i & 7;
    int lane = (i >> 3) & 63;
    int t    = (i >> 9) & 7;
    int s    = (i >> 12) & 3;
    int ks   = (i >> 14) & 1;
    int m = lane & 15, q = lane >> 4;
    int k = ks * 128 + 32 * s + 8 * q + j;
    int c = 16 * t + m;
    WtF[i] = f2bu(W[k * HD + c]);
  }
  if (i < INIT_ITEMS) cursor_s[i] = 0;
}

// ---------------- fused: GEMM blocks + XCD-sharded scatter blocks ------------
// r11 post-mortem: shard = blockIdx&7 cut writers/cell (16->2) but XCD-L2
// locality was only heuristic (dispatch order undefined). Now shard = PHYSICAL
// XCC_ID (s_getreg, HW-verified on gfx950): each shard's cursor (0.2MB) +
// slot (3.2MB) region is touched ONLY by blocks on that XCD -> lines stay
// exclusive in that XCD's 4MB L2 -> atomic+store become L2-local ops instead
// of cross-XCD line bounces. GEMM: round-5 ILP body (standalone ~10us; hides
// under the scatter stream).
__global__ __launch_bounds__(256, 2) void fused_gemm_scatter(
    const float* __restrict__ x,
    const unsigned short* __restrict__ WtF,  // fragment-linear bf16 [32768]
    const float* __restrict__ a_src,
    const float* __restrict__ a_dst,
    unsigned short* __restrict__ hbf,        // bf16 bits [N_NODES][HD]
    float* __restrict__ ssrc,
    float* __restrict__ sdst,
    const int2* __restrict__ adj,
    const float* __restrict__ wts,
    int* __restrict__ cursor_s,              // [NSH][N_NODES]
    unsigned int* __restrict__ slots_s) {    // [NSH][N_NODES][SCAP]
  __shared__ unsigned short xs[GROWS * LDKH];   // 17,408 B
  const int tid = threadIdx.x;

  if (blockIdx.x >= GEMM_BLOCKS) {
    // ---------------- scatter path (physical-XCD shard) ---------------------
    int e = (blockIdx.x - GEMM_BLOCKS) * 256 + tid;
    if (e >= N_EDGES) return;
    unsigned xcc;
    asm volatile("s_getreg_b32 %0, hwreg(HW_REG_XCC_ID)" : "=s"(xcc));
    const int shard = (int)(xcc & (NSH - 1));
    int2 sd = adj[e];                      // x = src, y = dst
    if ((unsigned)sd.x >= (unsigned)N_NODES || (unsigned)sd.y >= (unsigned)N_NODES) return;
    float g = fmaxf(wts[e], 1e-6f);
    int pos = atomicAdd(&cursor_s[shard * N_NODES + sd.y], 1);
    if (pos >= SCAP) pos = SCAP - 1;       // Poisson(2) tail ~1e-10/cell; never corrupt
    unsigned packed = ((unsigned)f2hu(g) << 16) | (unsigned)(sd.x & 0xffff);
    slots_s[((size_t)shard * N_NODES + sd.y) * SCAP + pos] = packed;
    return;
  }

  // ---------------- GEMM path (round-5 ILP body) ----------------------------
  const int row0 = blockIdx.x * GROWS;
  const int wid  = tid >> 6;      // wave id -> row stripe
  const int lane = tid & 63;
  const int m    = lane & 15;     // A row within tile / B col within tile
  const int q    = lane >> 4;     // quad

  float4 v0[8];
#pragma unroll
  for (int it = 0; it < 8; it++) {
    int i = it * 256 + tid, r = i >> 5, kq = i & 31;
    int row = row0 + r;
    v0[it] = (row < N_NODES) ? *(const float4*)(x + (size_t)row * DIN + 4 * kq)
                             : make_float4(0.f, 0.f, 0.f, 0.f);
  }
#pragma unroll
  for (int it = 0; it < 8; it++) {
    int i = it * 256 + tid, r = i >> 5, kq = i & 31;
    ushort4 b;
    b.x = f2bu(v0[it].x); b.y = f2bu(v0[it].y); b.z = f2bu(v0[it].z); b.w = f2bu(v0[it].w);
    *(ushort4*)&xs[r * LDKH + 4 * kq] = b;
  }
  __syncthreads();

  f32x4 acc[8];
#pragma unroll
  for (int t = 0; t < 8; t++) acc[t] = (f32x4){0.f, 0.f, 0.f, 0.f};

  const unsigned short* xbase = &xs[(wid * 16 + m) * LDKH];

  bf16x8 a0[4];
#pragma unroll
  for (int s = 0; s < 4; s++) a0[s] = *(const bf16x8*)(xbase + 32 * s + 8 * q);

  float4 v1[8];   // prefetch half 1 under half-0 MFMAs
#pragma unroll
  for (int it = 0; it < 8; it++) {
    int i = it * 256 + tid, r = i >> 5, kq = i & 31;
    int row = row0 + r;
    v1[it] = (row < N_NODES) ? *(const float4*)(x + (size_t)row * DIN + 128 + 4 * kq)
                             : make_float4(0.f, 0.f, 0.f, 0.f);
  }

#pragma unroll
  for (int s = 0; s < 4; s++) {
    bf16x8 bfr[8];
#pragma unroll
    for (int t = 0; t < 8; t++)
      bfr[t] = *(const bf16x8*)(WtF + (size_t)((0 * 4 + s) * 8 + t) * 512 + lane * 8);
#pragma unroll
    for (int t = 0; t < 8; t++)
      acc[t] = __builtin_amdgcn_mfma_f32_16x16x32_bf16(a0[s], bfr[t], acc[t], 0, 0, 0);
  }
  __syncthreads();   // all half-0 xs reads complete before overwrite

#pragma unroll
  for (int it = 0; it < 8; it++) {
    int i = it * 256 + tid, r = i >> 5, kq = i & 31;
    ushort4 b;
    b.x = f2bu(v1[it].x); b.y = f2bu(v1[it].y); b.z = f2bu(v1[it].z); b.w = f2bu(v1[it].w);
    *(ushort4*)&xs[r * LDKH + 4 * kq] = b;
  }
  __syncthreads();

  bf16x8 a1[4];
#pragma unroll
  for (int s = 0; s < 4; s++) a1[s] = *(const bf16x8*)(xbase + 32 * s + 8 * q);

#pragma unroll
  for (int s = 0; s < 4; s++) {
    bf16x8 bfr[8];
#pragma unroll
    for (int t = 0; t < 8; t++)
      bfr[t] = *(const bf16x8*)(WtF + (size_t)((1 * 4 + s) * 8 + t) * 512 + lane * 8);
#pragma unroll
    for (int t = 0; t < 8; t++)
      acc[t] = __builtin_amdgcn_mfma_f32_16x16x32_bf16(a1[s], bfr[t], acc[t], 0, 0, 0);
  }

  // D layout: lane holds rows q*4+r (r=0..3), col m of each tile t.
#pragma unroll
  for (int t = 0; t < 8; t++) {
#pragma unroll
    for (int r = 0; r < 4; r++) {
      int row = row0 + wid * 16 + q * 4 + r;
      if (row < N_NODES) hbf[(size_t)row * HD + 16 * t + m] = f2bu(acc[t][r]);
    }
  }

  float as[8], ad[8];
#pragma unroll
  for (int t = 0; t < 8; t++) {
    as[t] = a_src[16 * t + m];
    ad[t] = a_dst[16 * t + m];
  }
#pragma unroll
  for (int r = 0; r < 4; r++) {
    float ps[NH] = {0.f, 0.f, 0.f, 0.f};
    float pd[NH] = {0.f, 0.f, 0.f, 0.f};
#pragma unroll
    for (int t = 0; t < 8; t++) {
      ps[t >> 1] = fmaf(acc[t][r], as[t], ps[t >> 1]);
      pd[t >> 1] = fmaf(acc[t][r], ad[t], pd[t >> 1]);
    }
#pragma unroll
    for (int mm = 8; mm >= 1; mm >>= 1) {   // reduce across the 16 lanes of quad q
#pragma unroll
      for (int hh = 0; hh < NH; hh++) {
        ps[hh] += __shfl_xor(ps[hh], mm, 64);
        pd[hh] += __shfl_xor(pd[hh], mm, 64);
      }
    }
    int row = row0 + wid * 16 + q * 4 + r;
    if (m == 0 && row < N_NODES) {
#pragma unroll
      for (int hh = 0; hh < NH; hh++) {
        ssrc[row * NH + hh] = ps[hh];
        sdst[row * NH + hh] = pd[hh];
      }
    }
  }
}

// ---------------- per-node: WAVE-PARALLEL scores + aggregate + GELU ----------
// (unchanged from r11; node is gather-BW-bound near its L3-random floor)
__global__ __launch_bounds__(128, 4) void node_kernel(
    const int* __restrict__ cursor_s,         // [NSH][N_NODES]
    const unsigned int* __restrict__ slots_s, // [NSH][N_NODES][SCAP]
    const float* __restrict__ ssrc,           // [N_NODES][NH]
    const float* __restrict__ sdst,           // [N_NODES][NH]
    const unsigned int* __restrict__ hbf32,   // bf16 pairs
    float* __restrict__ out) {
  const int tid  = threadIdx.x;
  const int wid  = tid >> 6;           // 0/1: which node
  const int lane = tid & 63;
  const int n    = blockIdx.x * 2 + wid;
  const int hh   = lane >> 4;          // head for aggregation (cols 2l,2l+1)
  const int hq   = lane & 3;           // head for score phase

  __shared__ unsigned spk[2][CAP];          // gathered packed entries
  __shared__ float    swf[2][CAP * NH];     // alpha-numerator*gate per (edge,head)

  // ---- gather shard segments (8 independent guarded cell reads) ----
  int c[NSH], o[NSH];
  int tot = 0;
#pragma unroll
  for (int s = 0; s < NSH; s++) {
    int cs = cursor_s[s * N_NODES + n];   // wave-uniform address -> broadcast
    cs = (cs < SCAP) ? cs : SCAP;
    c[s] = cs;
    o[s] = tot;
    tot += cs;
  }
  const int deg = (tot < CAP) ? tot : CAP;
#pragma unroll
  for (int s = 0; s < NSH; s++) {
    if (lane < c[s]) {
      int d = o[s] + lane;
      if (d < CAP)
        spk[wid][d] = slots_s[((size_t)s * N_NODES + n) * SCAP + lane];
    }
  }
  __syncthreads();   // spk visible

  // ---- scores: all 64 lanes, chunk of 16 edges x 4 heads ----
  const float sdn = sdst[n * NH + hq];
  float den = 0.f;
  for (int base = 0; base < deg; base += 16) {
    int e = base + (lane >> 2);
    float exv = 0.f;
    if (e < deg) {
      unsigned sl = spk[wid][e];
      int s = (int)(sl & 0xffffu);
      float g = hu2f((unsigned short)(sl >> 16));
      float xx = ssrc[s * NH + hq] + sdn;
      // tanh via exp: 1 - 2/(1+e^{2x}); exact at +-inf, ~1e-7 abs err
      float t = 1.f - 2.f / (1.f + __expf(2.f * xx));
      exv = g * __expf(t);
      swf[wid][e * NH + hq] = exv * g;
    }
    den += exv;
  }
  // reduce across the 16 lanes sharing head hq (xor over bits 2..5)
  den += __shfl_xor(den, 4, 64);
  den += __shfl_xor(den, 8, 64);
  den += __shfl_xor(den, 16, 64);
  den += __shfl_xor(den, 32, 64);
  // lane needs head hh = lane>>4; source lane index hh has hq == hh
  float dh  = __shfl(den, hh, 64);
  float inv = (dh > 0.f) ? 1.f / dh : 0.f;
  __syncthreads();   // swf visible

  // ---- aggregation: unroll-8 gather windows ----
  float acc0 = 0.f, acc1 = 0.f;
  int j = 0;
  for (; j + 8 <= deg; j += 8) {
    int s0 = (int)(spk[wid][j + 0] & 0xffffu), s1 = (int)(spk[wid][j + 1] & 0xffffu);
    int s2 = (int)(spk[wid][j + 2] & 0xffffu), s3 = (int)(spk[wid][j + 3] & 0xffffu);
    int s4 = (int)(spk[wid][j + 4] & 0xffffu), s5 = (int)(spk[wid][j + 5] & 0xffffu);
    int s6 = (int)(spk[wid][j + 6] & 0xffffu), s7 = (int)(spk[wid][j + 7] & 0xffffu);
    unsigned u0 = hbf32[(size_t)s0 * (HD / 2) + lane];
    unsigned u1 = hbf32[(size_t)s1 * (HD / 2) + lane];
    unsigned u2 = hbf32[(size_t)s2 * (HD / 2) + lane];
    unsigned u3 = hbf32[(size_t)s3 * (HD / 2) + lane];
    unsigned u4 = hbf32[(size_t)s4 * (HD / 2) + lane];
    unsigned u5 = hbf32[(size_t)s5 * (HD / 2) + lane];
    unsigned u6 = hbf32[(size_t)s6 * (HD / 2) + lane];
    unsigned u7 = hbf32[(size_t)s7 * (HD / 2) + lane];
    float w0 = swf[wid][(j + 0) * NH + hh];
    float w1 = swf[wid][(j + 1) * NH + hh];
    float w2 = swf[wid][(j + 2) * NH + hh];
    float w3 = swf[wid][(j + 3) * NH + hh];
    float w4 = swf[wid][(j + 4) * NH + hh];
    float w5 = swf[wid][(j + 5) * NH + hh];
    float w6 = swf[wid][(j + 6) * NH + hh];
    float w7 = swf[wid][(j + 7) * NH + hh];
    acc0 = fmaf(w0, __uint_as_float(u0 << 16), acc0);
    acc1 = fmaf(w0, __uint_as_float(u0 & 0xffff0000u), acc1);
    acc0 = fmaf(w1, __uint_as_float(u1 << 16), acc0);
    acc1 = fmaf(w1, __uint_as_float(u1 & 0xffff0000u), acc1);
    acc0 = fmaf(w2, __uint_as_float(u2 << 16), acc0);
    acc1 = fmaf(w2, __uint_as_float(u2 & 0xffff0000u), acc1);
    acc0 = fmaf(w3, __uint_as_float(u3 << 16), acc0);
    acc1 = fmaf(w3, __uint_as_float(u3 & 0xffff0000u), acc1);
    acc0 = fmaf(w4, __uint_as_float(u4 << 16), acc0);
    acc1 = fmaf(w4, __uint_as_float(u4 & 0xffff0000u), acc1);
    acc0 = fmaf(w5, __uint_as_float(u5 << 16), acc0);
    acc1 = fmaf(w5, __uint_as_float(u5 & 0xffff0000u), acc1);
    acc0 = fmaf(w6, __uint_as_float(u6 << 16), acc0);
    acc1 = fmaf(w6, __uint_as_float(u6 & 0xffff0000u), acc1);
    acc0 = fmaf(w7, __uint_as_float(u7 << 16), acc0);
    acc1 = fmaf(w7, __uint_as_float(u7 & 0xffff0000u), acc1);
  }
  for (; j < deg; j++) {
    int s0 = (int)(spk[wid][j] & 0xffffu);
    unsigned u0 = hbf32[(size_t)s0 * (HD / 2) + lane];
    float w0 = swf[wid][j * NH + hh];
    acc0 = fmaf(w0, __uint_as_float(u0 << 16), acc0);
    acc1 = fmaf(w0, __uint_as_float(u0 & 0xffff0000u), acc1);
  }
  acc0 *= inv;
  acc1 *= inv;

  // exact GELU: x * 0.5 * (1 + erf(x/sqrt(2)))
  float2 gl;
  gl.x = 0.5f * acc0 * (1.f + erff(acc0 * 0.70710678118654752f));
  gl.y = 0.5f * acc1 * (1.f + erff(acc1 * 0.70710678118654752f));
  *(float2*)&out[(size_t)n * HD + 2 * lane] = gl;
}

extern "C" void kernel_launch(void* const* d_in, const int* in_sizes, int n_in,
                              void* d_out, int out_size, void* d_ws, size_t ws_size,
                              hipStream_t stream) {
  const float* x     = (const float*)d_in[0];
  const int2*  adj   = (const int2*)d_in[1];
  const float* wts   = (const float*)d_in[2];
  const float* W     = (const float*)d_in[3];
  const float* a_src = (const float*)d_in[4];
  const float* a_dst = (const float*)d_in[5];
  float* out = (float*)d_out;

  char* p = (char*)d_ws;
  auto carve = [&](size_t bytes) {
    char* q = p;
    p += (bytes + 255) & ~(size_t)255;
    return (void*)q;
  };
  // total ~ 42.5 MB
  unsigned short* hbf = (unsigned short*)carve((size_t)N_NODES * HD * sizeof(unsigned short)); // 12.8 MB
  unsigned short* WtF = (unsigned short*)carve((size_t)HD * DIN * sizeof(unsigned short));     // 64 KB
  float* ssrc   = (float*)carve((size_t)N_NODES * NH * sizeof(float));        // 0.8 MB
  float* sdst   = (float*)carve((size_t)N_NODES * NH * sizeof(float));        // 0.8 MB
  unsigned int* slots_s = (unsigned int*)carve((size_t)NSH * N_NODES * SCAP * sizeof(unsigned int)); // 25.6 MB
  int* cursor_s = (int*)carve((size_t)NSH * N_NODES * sizeof(int));           // 1.6 MB

  init_kernel<<<(INIT_ITEMS + 255) / 256, 256, 0, stream>>>(W, WtF, cursor_s);
  fused_gemm_scatter<<<GEMM_BLOCKS + SCAT_BLOCKS, 256, 0, stream>>>(
      x, WtF, a_src, a_dst, hbf, ssrc, sdst, adj, wts, cursor_s, slots_s);
  node_kernel<<<N_NODES / 2, 128, 0, stream>>>(cursor_s, slots_s, ssrc, sdst,
                                               (const unsigned int*)hbf, out);
}